// Round 6
// baseline (130.762 us; speedup 1.0000x reference)
//
#include <hip/hip_runtime.h>
#include <stdint.h>

typedef _Float16 half8 __attribute__((ext_vector_type(8)));
typedef float floatx4 __attribute__((ext_vector_type(4)));
typedef uint32_t u32x4 __attribute__((ext_vector_type(4)));

#define IF 512
#define NF 512
#define KT_TOTAL 72   // 8 base + 64 spline K-tiles of 64

__device__ __forceinline__ uint32_t pk(float a, float b) {
  return __builtin_bit_cast(uint32_t, __builtin_amdgcn_cvt_pkrtz(a, b));
}

// full 8-wide uniform cubic B-spline basis vector for one x, as 8 packed fp16
// grid knots: -2.2 + 0.4*t ; u = (x+2.2)*2.5 in [3,8) ; 4 nonzero weights at l=j3..j3+3
__device__ __forceinline__ u32x4 BASIS8(float xv) {
  float u = (xv + 2.2f) * 2.5f;
  float fj = __builtin_floorf(u);
  fj = fminf(fmaxf(fj, 3.0f), 7.0f);
  float t = u - fj;
  float omt = 1.0f - t;
  float t2 = t * t, t3 = t2 * t;
  float w0 = omt * omt * omt * 0.16666666666666666f;
  float w1 = __builtin_fmaf(0.5f, t3, 0.66666666666666666f - t2);
  float w2 = __builtin_fmaf(0.5f, (t2 - t3) + t, 0.16666666666666666f);
  float w3 = t3 * 0.16666666666666666f;
  uint32_t c0 = pk(w0, w1);
  uint32_t c1 = pk(w2, w3);
  int j3 = (int)fj - 3;                     // 0..4
  int sh = j3 << 4;                          // halfword shift in bits {0,16,32,48,64}
  uint64_t w = (uint64_t)c0 | ((uint64_t)c1 << 32);
  uint64_t lo = (sh < 64) ? (w << sh) : 0ull;
  uint64_t hi = (sh == 0) ? 0ull : ((sh < 64) ? (w >> (64 - sh)) : w);
  u32x4 r;
  r.x = (uint32_t)lo; r.y = (uint32_t)(lo >> 32);
  r.z = (uint32_t)hi; r.w = (uint32_t)(hi >> 32);
  return r;
}

// ---- zero d_out ----
__global__ __launch_bounds__(256)
void kan_zero(float4* __restrict__ p, int n4) {
  const int stride = gridDim.x * 256;
  for (int i = blockIdx.x * 256 + threadIdx.x; i < n4; i += stride)
    p[i] = (float4){0.f, 0.f, 0.f, 0.f};
}

// ---- prepass: pack weights fp16 into per-(kt,ns) 8KB tiles in lane-fragment order
// chunk q = (ni*2+kk)*64 + hi*16 + rr  holds B[ns*64+ni*16+rr][kt*64+kk*32+hi*8 .. +7]
__global__ __launch_bounds__(256)
void kan_prep(const float* __restrict__ bwg, const float* __restrict__ swg,
              u32x4* __restrict__ wsB)
{
  const int gid = blockIdx.x * 256 + threadIdx.x;   // 294912 chunks
  const int q  = gid & 511;
  const int Tn = gid >> 9;          // kt*8+ns
  const int kt = Tn >> 3, ns = Tn & 7;
  const int p  = q >> 6;            // ni*2+kk
  const int hi = (q >> 4) & 3, rr = q & 15;
  const int kk = p & 1, ni = p >> 1;
  const int n  = ns * 64 + ni * 16 + rr;
  const int ks = kk * 32 + hi * 8;
  const float* src = (kt < 8) ? bwg + (size_t)n * IF + kt * 64 + ks
                              : swg + (size_t)n * 4096 + (kt - 8) * 64 + ks;
  float4 f0 = ((const float4*)src)[0];
  float4 f1 = ((const float4*)src)[1];
  u32x4 v; v.x = pk(f0.x, f0.y); v.y = pk(f0.z, f0.w);
           v.z = pk(f1.x, f1.y); v.w = pk(f1.z, f1.w);
  wsB[gid] = v;
}

// ---- main: barrier-free, LDS-free; A in registers (basis / direct cvt) ----
__global__ __launch_bounds__(256, 4)
void kan_fused(const float* __restrict__ xg, const uint32_t* __restrict__ wsB,
               float* __restrict__ outg)
{
  const int tid = threadIdx.x, lane = tid & 63, widx = tid >> 6;
  // 1024 blocks: XCD-major so each XCD owns one n-strip (576KB B slice, L2-resident)
  const int bid = blockIdx.x;
  const int u = (bid & 7) * 128 + (bid >> 3);
  const int ns  = u >> 7;           // 0..7  n-strip (64 cols)
  const int kz  = (u >> 6) & 1;     // K-split half
  const int msb = u & 63;
  const int ms  = msb * 4 + widx;   // 0..255: 32-row strip per wave
  const int rr = lane & 15, hi = lane >> 4;

  const float* xr0 = xg + (size_t)(ms * 32 + rr) * IF;        // mi=0 row
  const float* xr1 = xr0 + (size_t)16 * IF;                   // mi=1 row
  const char*  bbase = (const char*)wsB + (size_t)ns * 8192 + (size_t)lane * 16;

  floatx4 acc[2][4];
#pragma unroll
  for (int mi = 0; mi < 2; ++mi)
#pragma unroll
    for (int ni = 0; ni < 4; ++ni)
      acc[mi][ni] = (floatx4){0.f, 0.f, 0.f, 0.f};

  // ---- base tiles (kz==0 only): A = x cast to fp16, straight from global ----
  if (kz == 0) {
#pragma unroll 1
    for (int kt = 0; kt < 8; ++kt) {
      const char* bp = bbase + (size_t)kt * 65536;
      u32x4 b[8];
#pragma unroll
      for (int j = 0; j < 8; ++j) b[j] = *(const u32x4*)(bp + j * 1024);
#pragma unroll
      for (int mi = 0; mi < 2; ++mi) {
        const float* xr = mi ? xr1 : xr0;
#pragma unroll
        for (int kk = 0; kk < 2; ++kk) {
          const float* s = xr + kt * 64 + kk * 32 + hi * 8;
          float4 f0 = ((const float4*)s)[0];
          float4 f1 = ((const float4*)s)[1];
          u32x4 av; av.x = pk(f0.x, f0.y); av.y = pk(f0.z, f0.w);
                    av.z = pk(f1.x, f1.y); av.w = pk(f1.z, f1.w);
          half8 a = __builtin_bit_cast(half8, av);
#pragma unroll
          for (int ni = 0; ni < 4; ++ni)
            acc[mi][ni] = __builtin_amdgcn_mfma_f32_16x16x32_f16(
                a, __builtin_bit_cast(half8, b[ni * 2 + kk]), acc[mi][ni], 0, 0, 0);
        }
      }
    }
  }

  // ---- spline tiles: A-fragment = BASIS8(x[row, i]) computed in registers ----
  const int ktS0 = kz ? 36 : 8, ktS1 = kz ? 72 : 36;
  float xc[4], xn[4];
  {
    const int i0 = (ktS0 - 8) * 8;
#pragma unroll
    for (int mi = 0; mi < 2; ++mi)
#pragma unroll
      for (int kk = 0; kk < 2; ++kk)
        xc[mi * 2 + kk] = (mi ? xr1 : xr0)[i0 + kk * 4 + hi];
  }
#pragma unroll 1
  for (int kt = ktS0; kt < ktS1; ++kt) {
    const char* bp = bbase + (size_t)kt * 65536;
    u32x4 b[8];
#pragma unroll
    for (int j = 0; j < 8; ++j) b[j] = *(const u32x4*)(bp + j * 1024);
    // prefetch next tile's x AFTER B-loads (in-order vmcnt: B-waits won't touch these)
    const int ktn = (kt + 1 < ktS1) ? (kt + 1) : kt;
    const int i0n = (ktn - 8) * 8;
#pragma unroll
    for (int mi = 0; mi < 2; ++mi)
#pragma unroll
      for (int kk = 0; kk < 2; ++kk)
        xn[mi * 2 + kk] = (mi ? xr1 : xr0)[i0n + kk * 4 + hi];
    // basis VALU (~130 instr) hides the B-load L2 latency, then MFMA
#pragma unroll
    for (int mi = 0; mi < 2; ++mi)
#pragma unroll
      for (int kk = 0; kk < 2; ++kk) {
        half8 a = __builtin_bit_cast(half8, BASIS8(xc[mi * 2 + kk]));
#pragma unroll
        for (int ni = 0; ni < 4; ++ni)
          acc[mi][ni] = __builtin_amdgcn_mfma_f32_16x16x32_f16(
              a, __builtin_bit_cast(half8, b[ni * 2 + kk]), acc[mi][ni], 0, 0, 0);
      }
#pragma unroll
    for (int q2 = 0; q2 < 4; ++q2) xc[q2] = xn[q2];
  }

  // ---- epilogue: C/D col=lane&15, row=(lane>>4)*4+e ; split-K atomic accumulate
#pragma unroll
  for (int mi = 0; mi < 2; ++mi)
#pragma unroll
    for (int ni = 0; ni < 4; ++ni) {
      const size_t base = (size_t)(ms * 32 + mi * 16 + hi * 4) * NF
                        + (size_t)(ns * 64 + ni * 16 + rr);
#pragma unroll
      for (int e = 0; e < 4; ++e)
        unsafeAtomicAdd(outg + base + (size_t)e * NF, acc[mi][ni][e]);
    }
}

extern "C" void kernel_launch(void* const* d_in, const int* in_sizes, int n_in,
                              void* d_out, int out_size, void* d_ws, size_t ws_size,
                              hipStream_t stream) {
  const float* x  = (const float*)d_in[0];
  const float* bw = (const float*)d_in[1];
  const float* sw = (const float*)d_in[2];
  float* out = (float*)d_out;
  u32x4* wsB = (u32x4*)d_ws;   // 72*8*8KB = 4.5 MB
  hipLaunchKernelGGL(kan_zero, dim3(2048), dim3(256), 0, stream, (float4*)out, out_size / 4);
  hipLaunchKernelGGL(kan_prep, dim3(1152), dim3(256), 0, stream, bw, sw, wsB);
  hipLaunchKernelGGL(kan_fused, dim3(1024), dim3(256), 0, stream, x, (const uint32_t*)wsB, out);
}

// Round 7
// 125.258 us; speedup vs baseline: 1.0439x; 1.0439x over previous
//
#include <hip/hip_runtime.h>
#include <stdint.h>

typedef _Float16 half8 __attribute__((ext_vector_type(8)));
typedef float floatx4 __attribute__((ext_vector_type(4)));
typedef uint32_t u32x4 __attribute__((ext_vector_type(4)));

#define IF 512
#define NF 512

__device__ __forceinline__ uint32_t pk(float a, float b) {
  return __builtin_bit_cast(uint32_t, __builtin_amdgcn_cvt_pkrtz(a, b));
}

// full 8-wide uniform cubic B-spline basis vector for one x, as 8 packed fp16
// grid knots: -2.2 + 0.4*t ; u = (x+2.2)*2.5 in [3,8) ; 4 nonzero weights at l=j3..j3+3
__device__ __forceinline__ u32x4 BASIS8(float xv) {
  float u = (xv + 2.2f) * 2.5f;
  float fj = __builtin_floorf(u);
  fj = fminf(fmaxf(fj, 3.0f), 7.0f);
  float t = u - fj;
  float omt = 1.0f - t;
  float t2 = t * t, t3 = t2 * t;
  float w0 = omt * omt * omt * 0.16666666666666666f;
  float w1 = __builtin_fmaf(0.5f, t3, 0.66666666666666666f - t2);
  float w2 = __builtin_fmaf(0.5f, (t2 - t3) + t, 0.16666666666666666f);
  float w3 = t3 * 0.16666666666666666f;
  uint32_t c0 = pk(w0, w1);
  uint32_t c1 = pk(w2, w3);
  int j3 = (int)fj - 3;                      // 0..4
  int sh = j3 << 4;                          // halfword shift {0,16,32,48,64}
  uint64_t w = (uint64_t)c0 | ((uint64_t)c1 << 32);
  uint64_t lo = (sh < 64) ? (w << sh) : 0ull;
  uint64_t hi = (sh == 0) ? 0ull : ((sh < 64) ? (w >> (64 - sh)) : w);
  u32x4 r;
  r.x = (uint32_t)lo; r.y = (uint32_t)(lo >> 32);
  r.z = (uint32_t)hi; r.w = (uint32_t)(hi >> 32);
  return r;
}

// ---- zero d_out ----
__global__ __launch_bounds__(256)
void kan_zero(float4* __restrict__ p, int n4) {
  const int stride = gridDim.x * 256;
  for (int i = blockIdx.x * 256 + threadIdx.x; i < n4; i += stride)
    p[i] = (float4){0.f, 0.f, 0.f, 0.f};
}

// ---- prepass B: pack weights fp16 into per-(kt,ns) 8KB tiles in lane-fragment order
// chunk q = (ni*2+kk)*64 + hi*16 + rr holds B[ns*64+ni*16+rr][kt*64+kk*32+hi*8 .. +7]
__global__ __launch_bounds__(256)
void kan_prepB(const float* __restrict__ bwg, const float* __restrict__ swg,
               u32x4* __restrict__ wsB)
{
  const int gid = blockIdx.x * 256 + threadIdx.x;   // 294912 chunks
  const int q  = gid & 511;
  const int Tn = gid >> 9;          // kt*8+ns
  const int kt = Tn >> 3, ns = Tn & 7;
  const int p  = q >> 6;            // ni*2+kk
  const int hi = (q >> 4) & 3, rr = q & 15;
  const int kk = p & 1, ni = p >> 1;
  const int n  = ns * 64 + ni * 16 + rr;
  const int ks = kk * 32 + hi * 8;
  const float* src = (kt < 8) ? bwg + (size_t)n * IF + kt * 64 + ks
                              : swg + (size_t)n * 4096 + (kt - 8) * 64 + ks;
  float4 f0 = ((const float4*)src)[0];
  float4 f1 = ((const float4*)src)[1];
  u32x4 v; v.x = pk(f0.x, f0.y); v.y = pk(f0.z, f0.w);
           v.z = pk(f1.x, f1.y); v.w = pk(f1.z, f1.w);
  wsB[gid] = v;
}

// ---- prepass A: base-weight-phase A planes: wsA[p*8192+b] = fp16 x[b][p*8..+7]
__global__ __launch_bounds__(256)
void kan_prepA(const float* __restrict__ xg, u32x4* __restrict__ wsA)
{
  const int gid = blockIdx.x * 256 + threadIdx.x;   // 524288 chunks
  const int b = gid >> 6, p = gid & 63;
  const float* s = xg + (size_t)b * IF + p * 8;
  float4 f0 = ((const float4*)s)[0];
  float4 f1 = ((const float4*)s)[1];
  u32x4 v; v.x = pk(f0.x, f0.y); v.y = pk(f0.z, f0.w);
           v.z = pk(f1.x, f1.y); v.w = pk(f1.z, f1.w);
  wsA[(size_t)p * 8192 + b] = v;
}

// ---- main: barrier-free, LDS-free, 2-deep register-pipelined ----
__global__ __launch_bounds__(256, 3)
void kan_fused(const float* __restrict__ xg, const u32x4* __restrict__ wsB,
               const u32x4* __restrict__ wsA, float* __restrict__ outg)
{
  const int tid = threadIdx.x, lane = tid & 63, widx = tid >> 6;
  // 1024 blocks: XCD-major so each XCD owns one n-strip (B slice L2-resident)
  const int bid = blockIdx.x;
  const int u = (bid & 7) * 128 + (bid >> 3);
  const int ns  = u >> 7;           // 0..7  n-strip (64 cols) == XCD id
  const int kz  = (u >> 6) & 1;     // K-split half
  const int msb = u & 63;
  const int ms  = msb * 4 + widx;   // 0..255: 32-row strip per wave
  const int rr = lane & 15, hi = lane >> 4;

  const float* xr0 = xg + (size_t)(ms * 32 + rr) * IF;
  const char*  bbase = (const char*)wsB + (size_t)ns * 8192 + (size_t)lane * 16;
  const char*  abase = (const char*)wsA + (size_t)hi * 131072 + (size_t)(ms * 32 + rr) * 16;

  floatx4 acc[2][4];
#pragma unroll
  for (int mi = 0; mi < 2; ++mi)
#pragma unroll
    for (int ni = 0; ni < 4; ++ni)
      acc[mi][ni] = (floatx4){0.f, 0.f, 0.f, 0.f};

  auto LOADB = [&](int kt, u32x4* b) {
    const char* bp = bbase + (size_t)kt * 65536;
#pragma unroll
    for (int j = 0; j < 8; ++j) b[j] = *(const u32x4*)(bp + j * 1024);
  };
  auto LOADA = [&](int kt, u32x4* a) {   // base tiles (kt<8)
#pragma unroll
    for (int mi = 0; mi < 2; ++mi)
#pragma unroll
      for (int kk = 0; kk < 2; ++kk)
        a[mi * 2 + kk] = *(const u32x4*)(abase + (size_t)kt * 1048576
                                               + (size_t)kk * 524288 + (size_t)mi * 256);
  };
  auto LOADX = [&](int kt, float* xv) {  // spline tiles (kt>=8)
    const int i0 = (kt - 8) * 8;
#pragma unroll
    for (int mi = 0; mi < 2; ++mi)
#pragma unroll
      for (int kk = 0; kk < 2; ++kk)
        xv[mi * 2 + kk] = xr0[(size_t)mi * 16 * IF + i0 + kk * 4 + hi];
  };
  auto MFMA16 = [&](const u32x4* a, const u32x4* b) {
#pragma unroll
    for (int mi = 0; mi < 2; ++mi)
#pragma unroll
      for (int kk = 0; kk < 2; ++kk) {
        half8 av = __builtin_bit_cast(half8, a[mi * 2 + kk]);
#pragma unroll
        for (int ni = 0; ni < 4; ++ni)
          acc[mi][ni] = __builtin_amdgcn_mfma_f32_16x16x32_f16(
              av, __builtin_bit_cast(half8, b[ni * 2 + kk]), acc[mi][ni], 0, 0, 0);
      }
  };

  // ---- base tiles (kz==0): A from wsA planes, 2-deep ping-pong ----
  if (kz == 0) {
    u32x4 a0[4], a1[4], b0[8], b1[8];
    LOADA(0, a0); LOADB(0, b0);
#pragma unroll 1
    for (int kt = 0; kt < 8; kt += 2) {
      LOADA(kt + 1, a1); LOADB(kt + 1, b1);     // issue t+1 before compute t
      MFMA16(a0, b0);
      const int k2 = (kt + 2 < 8) ? kt + 2 : 0; // last-iter loads harmless
      LOADA(k2, a0); LOADB(k2, b0);
      MFMA16(a1, b1);
    }
  }

  // ---- spline tiles: A = BASIS8(x) in-register, 2-deep ping-pong ----
  {
    const int s0 = kz ? 36 : 8, s1 = kz ? 72 : 36;
    u32x4 b0[8], b1[8], af[4];
    float x0[4], x1[4];
    LOADB(s0, b0); LOADX(s0, x0);
#pragma unroll 1
    for (int kt = s0; kt < s1; kt += 2) {
      LOADB(kt + 1, b1); LOADX(kt + 1, x1);     // issue t+1
#pragma unroll
      for (int q = 0; q < 4; ++q) af[q] = BASIS8(x0[q]);  // VALU hides latency
      MFMA16(af, b0);
      const int k2 = (kt + 2 < s1) ? kt + 2 : s0;
      LOADB(k2, b0); LOADX(k2, x0);             // issue t+2
#pragma unroll
      for (int q = 0; q < 4; ++q) af[q] = BASIS8(x1[q]);
      MFMA16(af, b1);
    }
  }

  // ---- epilogue: C/D col=lane&15, row=(lane>>4)*4+e ; split-K atomic accumulate
#pragma unroll
  for (int mi = 0; mi < 2; ++mi)
#pragma unroll
    for (int ni = 0; ni < 4; ++ni) {
      const size_t base = (size_t)(ms * 32 + mi * 16 + hi * 4) * NF
                        + (size_t)(ns * 64 + ni * 16 + rr);
#pragma unroll
      for (int e = 0; e < 4; ++e)
        unsafeAtomicAdd(outg + base + (size_t)e * NF, acc[mi][ni][e]);
    }
}

extern "C" void kernel_launch(void* const* d_in, const int* in_sizes, int n_in,
                              void* d_out, int out_size, void* d_ws, size_t ws_size,
                              hipStream_t stream) {
  const float* x  = (const float*)d_in[0];
  const float* bw = (const float*)d_in[1];
  const float* sw = (const float*)d_in[2];
  float* out = (float*)d_out;
  u32x4* wsB = (u32x4*)d_ws;                              // 4.5 MB
  u32x4* wsA = (u32x4*)((char*)d_ws + 4718592);           // 8 MB
  hipLaunchKernelGGL(kan_zero,  dim3(2048), dim3(256), 0, stream, (float4*)out, out_size / 4);
  hipLaunchKernelGGL(kan_prepB, dim3(1152), dim3(256), 0, stream, bw, sw, wsB);
  hipLaunchKernelGGL(kan_prepA, dim3(2048), dim3(256), 0, stream, x, wsA);
  hipLaunchKernelGGL(kan_fused, dim3(1024), dim3(256), 0, stream, x, wsB, wsA, out);
}

// Round 8
// 97.803 us; speedup vs baseline: 1.3370x; 1.2807x over previous
//
#include <hip/hip_runtime.h>
#include <stdint.h>

typedef _Float16 half8 __attribute__((ext_vector_type(8)));
typedef float floatx4 __attribute__((ext_vector_type(4)));
typedef uint32_t u32x4 __attribute__((ext_vector_type(4)));

#define IF 512
#define NF 512
#define KT_TOTAL 72          // 8 base + 64 spline K-tiles of 64
#define TILE_B 16384         // bytes per 128x64 fp16 tile image
#define B_WS_BYTES ((size_t)KT_TOTAL * 4 * TILE_B)   // 4.5 MB

__device__ __forceinline__ uint32_t swz(uint32_t b) {
  // rows are 128B; XOR byte bits [6:4] with (row&7): kills ds_read_b128 conflicts
  return b ^ (((b >> 7) & 7u) << 4);
}
__device__ __forceinline__ uint32_t pk(float a, float b) {
  return __builtin_bit_cast(uint32_t, __builtin_amdgcn_cvt_pkrtz(a, b));
}

// 8-wide uniform cubic B-spline basis for one x, packed fp16 (verified R5-R7)
__device__ __forceinline__ u32x4 BASIS8(float xv) {
  float u = (xv + 2.2f) * 2.5f;
  float fj = __builtin_floorf(u);
  fj = fminf(fmaxf(fj, 3.0f), 7.0f);
  float t = u - fj;
  float omt = 1.0f - t;
  float t2 = t * t, t3 = t2 * t;
  float w0 = omt * omt * omt * 0.16666666666666666f;
  float w1 = __builtin_fmaf(0.5f, t3, 0.66666666666666666f - t2);
  float w2 = __builtin_fmaf(0.5f, (t2 - t3) + t, 0.16666666666666666f);
  float w3 = t3 * 0.16666666666666666f;
  uint32_t c0 = pk(w0, w1);
  uint32_t c1 = pk(w2, w3);
  int j3 = (int)fj - 3;                      // 0..4
  int sh = j3 << 4;                          // halfword shift {0,16,32,48,64}
  uint64_t w = (uint64_t)c0 | ((uint64_t)c1 << 32);
  uint64_t lo = (sh < 64) ? (w << sh) : 0ull;
  uint64_t hi = (sh == 0) ? 0ull : ((sh < 64) ? (w >> (64 - sh)) : w);
  u32x4 r;
  r.x = (uint32_t)lo; r.y = (uint32_t)(lo >> 32);
  r.z = (uint32_t)hi; r.w = (uint32_t)(hi >> 32);
  return r;
}

// ---- zero d_out ----
__global__ __launch_bounds__(256)
void kan_zero(float4* __restrict__ p, int n4) {
  const int stride = gridDim.x * 256;
  for (int i = blockIdx.x * 256 + threadIdx.x; i < n4; i += stride)
    p[i] = (float4){0.f, 0.f, 0.f, 0.f};
}

// ---- prepass B: weights -> fp16 128x64 tile images, pre-swizzled (R5-verified)
__global__ __launch_bounds__(256)
void kan_prepB(const float* __restrict__ bwg, const float* __restrict__ swg,
               uint8_t* __restrict__ wsB)
{
  const int gid = blockIdx.x * 256 + threadIdx.x;  // one per 16B chunk
  const int T = gid >> 10;          // tile kt*4+nt, 0..287
  const int q = gid & 1023;
  const int kt = T >> 2;
  const int nt = T & 3;
  const uint32_t p = swz((uint32_t)q * 16u);
  const int row = p >> 7;           // n within tile
  const int c   = (p & 127) >> 1;   // k within tile (mult of 8)
  const int n = nt * 128 + row;
  const float* src = (kt < 8) ? bwg + (size_t)n * IF + kt * 64 + c
                              : swg + (size_t)n * 4096 + (kt - 8) * 64 + c;
  float4 f0 = ((const float4*)src)[0];
  float4 f1 = ((const float4*)src)[1];
  u32x4 v; v.x = pk(f0.x, f0.y); v.y = pk(f0.z, f0.w);
           v.z = pk(f1.x, f1.y); v.w = pk(f1.z, f1.w);
  *(u32x4*)(wsB + (size_t)T * TILE_B + (size_t)q * 16) = v;
}

// ---- prepass A: x-cast + basis -> fp16 tile images (rows [row0,row0+R))
// thread = one 16B chunk: local row bl, chunk col c (0..575); c<64 base, else spline
__global__ __launch_bounds__(256)
void kan_prepA(const float* __restrict__ xg, uint8_t* __restrict__ wsA, int row0)
{
  const int gid = blockIdx.x * 256 + threadIdx.x;
  const int bl = gid / 576;
  const int c  = gid - bl * 576;
  const int b  = row0 + bl;
  u32x4 v;
  if (c < 64) {
    const float* s = xg + (size_t)b * IF + c * 8;
    float4 f0 = ((const float4*)s)[0];
    float4 f1 = ((const float4*)s)[1];
    v.x = pk(f0.x, f0.y); v.y = pk(f0.z, f0.w);
    v.z = pk(f1.x, f1.y); v.w = pk(f1.z, f1.w);
  } else {
    v = BASIS8(xg[(size_t)b * IF + (c - 64)]);
  }
  const int mt = bl >> 7;
  const int r  = bl & 127;
  const int kt = c >> 3;
  const uint32_t lin = (uint32_t)r * 128u + (uint32_t)(c & 7) * 16u;
  *(u32x4*)(wsA + (size_t)(mt * KT_TOTAL + kt) * TILE_B + swz(lin)) = v;
}

// ---- main: pure fp16 GEMM, m97 structure, split-K=2 ----
__global__ __launch_bounds__(512, 4)
void kan_gemm(const uint8_t* __restrict__ wsA, const uint8_t* __restrict__ wsB,
              float* __restrict__ outg, int row0, int mtBits)
{
  __shared__ _Float16 As[2][8192];
  __shared__ _Float16 Bs[2][8192];

  const int tid = threadIdx.x, lane = tid & 63, wv = tid >> 6;
  const int wm = wv >> 2, wn = wv & 3;

  // XCD-bijective swizzle; XCD owns one ntI strip -> B panel L2-resident
  const int cpx = gridDim.x >> 3;
  const int bid = blockIdx.x;
  const int u = (bid & 7) * cpx + (bid >> 3);
  const int kz = u & 1;
  const int lb = u >> 1;
  const int mt  = lb & ((1 << mtBits) - 1);
  const int ntI = lb >> mtBits;
  const int bm0 = row0 + mt * 128;
  const int bn0 = ntI * 128;
  const int kt0 = kz * 36, kt1 = kt0 + 36;

  char* AsB = (char*)As;
  char* BsB = (char*)Bs;

  uint32_t rdA[4], rdB[2];
  {
    const int rr = lane & 15;
    const uint32_t cc = (uint32_t)(lane >> 4) * 16u;
#pragma unroll
    for (int mi = 0; mi < 4; ++mi)
      rdA[mi] = swz((uint32_t)(wm * 64 + mi * 16 + rr) * 128u + cc);
#pragma unroll
    for (int ni = 0; ni < 2; ++ni)
      rdB[ni] = swz((uint32_t)(wn * 32 + ni * 16 + rr) * 128u + cc);
  }

  floatx4 acc[4][2];
#pragma unroll
  for (int mi = 0; mi < 4; ++mi)
#pragma unroll
    for (int ni = 0; ni < 2; ++ni)
      acc[mi][ni] = (floatx4){0.f, 0.f, 0.f, 0.f};

  auto STAGE = [&](int kt, int nb) {
    const uint8_t* sa = wsA + (size_t)(mt * KT_TOTAL + kt) * TILE_B + (size_t)tid * 16;
    const uint8_t* sb = wsB + (size_t)(kt * 4 + ntI) * TILE_B + (size_t)tid * 16;
    char* da = AsB + nb * TILE_B + tid * 16;
    char* db = BsB + nb * TILE_B + tid * 16;
    __builtin_amdgcn_global_load_lds((const __attribute__((address_space(1))) uint32_t*)sa,
                                     (__attribute__((address_space(3))) uint32_t*)da, 16, 0, 0);
    __builtin_amdgcn_global_load_lds((const __attribute__((address_space(1))) uint32_t*)(sa + 8192),
                                     (__attribute__((address_space(3))) uint32_t*)(da + 8192), 16, 0, 0);
    __builtin_amdgcn_global_load_lds((const __attribute__((address_space(1))) uint32_t*)sb,
                                     (__attribute__((address_space(3))) uint32_t*)db, 16, 0, 0);
    __builtin_amdgcn_global_load_lds((const __attribute__((address_space(1))) uint32_t*)(sb + 8192),
                                     (__attribute__((address_space(3))) uint32_t*)(db + 8192), 16, 0, 0);
  };

  auto COMPUTE = [&](int cb) {
    const char* ab = AsB + cb * TILE_B;
    const char* bb = BsB + cb * TILE_B;
#pragma unroll
    for (int kk = 0; kk < 2; ++kk) {
      const uint32_t ko = (uint32_t)(kk * 64);
      half8 a[4], b[2];
#pragma unroll
      for (int mi = 0; mi < 4; ++mi)
        a[mi] = *(const half8*)(ab + (rdA[mi] ^ ko));   // XOR: swizzle-safe
#pragma unroll
      for (int ni = 0; ni < 2; ++ni)
        b[ni] = *(const half8*)(bb + (rdB[ni] ^ ko));
#pragma unroll
      for (int mi = 0; mi < 4; ++mi)
#pragma unroll
        for (int ni = 0; ni < 2; ++ni)
          acc[mi][ni] = __builtin_amdgcn_mfma_f32_16x16x32_f16(a[mi], b[ni], acc[mi][ni], 0, 0, 0);
    }
  };

  STAGE(kt0, 0);
  __syncthreads();
#pragma unroll 1
  for (int kt = kt0; kt < kt1; ++kt) {
    const int cur = (kt - kt0) & 1;
    if (kt + 1 < kt1) STAGE(kt + 1, cur ^ 1);   // async DMA overlaps COMPUTE
    COMPUTE(cur);
    __syncthreads();                            // one barrier per K-step
  }

  // epilogue: C/D col=lane&15, row=(lane>>4)*4+e ; split-K atomic accumulate
  const int er = (lane >> 4) * 4;
  const int ec = lane & 15;
#pragma unroll
  for (int mi = 0; mi < 4; ++mi) {
#pragma unroll
    for (int ni = 0; ni < 2; ++ni) {
      const size_t base = (size_t)(bm0 + wm * 64 + mi * 16 + er) * NF
                        + (size_t)(bn0 + wn * 32 + ni * 16 + ec);
#pragma unroll
      for (int e = 0; e < 4; ++e)
        unsafeAtomicAdd(outg + base + (size_t)e * NF, acc[mi][ni][e]);
    }
  }
}

extern "C" void kernel_launch(void* const* d_in, const int* in_sizes, int n_in,
                              void* d_out, int out_size, void* d_ws, size_t ws_size,
                              hipStream_t stream) {
  const float* x  = (const float*)d_in[0];
  const float* bw = (const float*)d_in[1];
  const float* sw = (const float*)d_in[2];
  float* out = (float*)d_out;
  uint8_t* wsB = (uint8_t*)d_ws;
  uint8_t* wsA = wsB + B_WS_BYTES;

  // adaptive M-chunking: A images need R*4608*2 bytes
  int R = 8192;
  while (R > 512 && B_WS_BYTES + (size_t)R * 4608 * 2 > ws_size) R >>= 1;
  int mtBits = 31 - __builtin_clz(R / 128);

  hipLaunchKernelGGL(kan_zero,  dim3(2048), dim3(256), 0, stream, (float4*)out, out_size / 4);
  hipLaunchKernelGGL(kan_prepB, dim3(1152), dim3(256), 0, stream, bw, sw, wsB);
  for (int r0 = 0; r0 < 8192; r0 += R) {
    hipLaunchKernelGGL(kan_prepA, dim3(R * 576 / 256), dim3(256), 0, stream, x, wsA, r0);
    hipLaunchKernelGGL(kan_gemm,  dim3(R / 16), dim3(512), 0, stream, wsA, wsB, out, r0, mtBits);
  }
}

// Round 9
// 92.839 us; speedup vs baseline: 1.4085x; 1.0535x over previous
//
#include <hip/hip_runtime.h>
#include <stdint.h>

typedef _Float16 half8 __attribute__((ext_vector_type(8)));
typedef float floatx4 __attribute__((ext_vector_type(4)));
typedef uint32_t u32x4 __attribute__((ext_vector_type(4)));

#define IF 512
#define NF 512
#define KT_TOTAL 72          // 8 base + 64 spline K-tiles of 64
#define TILE_B 16384         // bytes per 128x64 fp16 tile image
#define B_WS_BYTES ((size_t)KT_TOTAL * 4 * TILE_B)   // 4.5 MB

__device__ __forceinline__ uint32_t swz(uint32_t b) {
  // rows are 128B; XOR byte bits [6:4] with (row&7): kills ds_read_b128 conflicts
  return b ^ (((b >> 7) & 7u) << 4);
}
__device__ __forceinline__ uint32_t pk(float a, float b) {
  return __builtin_bit_cast(uint32_t, __builtin_amdgcn_cvt_pkrtz(a, b));
}

// 8-wide uniform cubic B-spline basis for one x, packed fp16 (verified R5-R8)
__device__ __forceinline__ u32x4 BASIS8(float xv) {
  float u = (xv + 2.2f) * 2.5f;
  float fj = __builtin_floorf(u);
  fj = fminf(fmaxf(fj, 3.0f), 7.0f);
  float t = u - fj;
  float omt = 1.0f - t;
  float t2 = t * t, t3 = t2 * t;
  float w0 = omt * omt * omt * 0.16666666666666666f;
  float w1 = __builtin_fmaf(0.5f, t3, 0.66666666666666666f - t2);
  float w2 = __builtin_fmaf(0.5f, (t2 - t3) + t, 0.16666666666666666f);
  float w3 = t3 * 0.16666666666666666f;
  uint32_t c0 = pk(w0, w1);
  uint32_t c1 = pk(w2, w3);
  int j3 = (int)fj - 3;                      // 0..4
  int sh = j3 << 4;                          // halfword shift {0,16,32,48,64}
  uint64_t w = (uint64_t)c0 | ((uint64_t)c1 << 32);
  uint64_t lo = (sh < 64) ? (w << sh) : 0ull;
  uint64_t hi = (sh == 0) ? 0ull : ((sh < 64) ? (w >> (64 - sh)) : w);
  u32x4 r;
  r.x = (uint32_t)lo; r.y = (uint32_t)(lo >> 32);
  r.z = (uint32_t)hi; r.w = (uint32_t)(hi >> 32);
  return r;
}

// ---- zero d_out ----
__global__ __launch_bounds__(256)
void kan_zero(float4* __restrict__ p, int n4) {
  const int stride = gridDim.x * 256;
  for (int i = blockIdx.x * 256 + threadIdx.x; i < n4; i += stride)
    p[i] = (float4){0.f, 0.f, 0.f, 0.f};
}

// ---- prepass B: weights -> fp16 128x64 tile images, pre-swizzled (R5-verified)
__global__ __launch_bounds__(256)
void kan_prepB(const float* __restrict__ bwg, const float* __restrict__ swg,
               uint8_t* __restrict__ wsB)
{
  const int gid = blockIdx.x * 256 + threadIdx.x;  // one per 16B chunk
  const int T = gid >> 10;          // tile kt*4+nt, 0..287
  const int q = gid & 1023;
  const int kt = T >> 2;
  const int nt = T & 3;
  const uint32_t p = swz((uint32_t)q * 16u);
  const int row = p >> 7;           // n within tile
  const int c   = (p & 127) >> 1;   // k within tile (mult of 8)
  const int n = nt * 128 + row;
  const float* src = (kt < 8) ? bwg + (size_t)n * IF + kt * 64 + c
                              : swg + (size_t)n * 4096 + (kt - 8) * 64 + c;
  float4 f0 = ((const float4*)src)[0];
  float4 f1 = ((const float4*)src)[1];
  u32x4 v; v.x = pk(f0.x, f0.y); v.y = pk(f0.z, f0.w);
           v.z = pk(f1.x, f1.y); v.w = pk(f1.z, f1.w);
  *(u32x4*)(wsB + (size_t)T * TILE_B + (size_t)q * 16) = v;
}

// ---- prepass A: x-cast + basis -> fp16 tile images (rows [row0,row0+R))
__global__ __launch_bounds__(256)
void kan_prepA(const float* __restrict__ xg, uint8_t* __restrict__ wsA, int row0)
{
  const int gid = blockIdx.x * 256 + threadIdx.x;
  const int bl = gid / 576;
  const int c  = gid - bl * 576;
  const int b  = row0 + bl;
  u32x4 v;
  if (c < 64) {
    const float* s = xg + (size_t)b * IF + c * 8;
    float4 f0 = ((const float4*)s)[0];
    float4 f1 = ((const float4*)s)[1];
    v.x = pk(f0.x, f0.y); v.y = pk(f0.z, f0.w);
    v.z = pk(f1.x, f1.y); v.w = pk(f1.z, f1.w);
  } else {
    v = BASIS8(xg[(size_t)b * IF + (c - 64)]);
  }
  const int mt = bl >> 7;
  const int r  = bl & 127;
  const int kt = c >> 3;
  const uint32_t lin = (uint32_t)r * 128u + (uint32_t)(c & 7) * 16u;
  *(u32x4*)(wsA + (size_t)(mt * KT_TOTAL + kt) * TILE_B + swz(lin)) = v;
}

// ---- main: pure fp16 GEMM, m97 structure, split-K=2 ----
// Block mapping: XCD x owns a CONTIGUOUS mt range; all 8 (ntI,kz) blocks of an
// mt sit on the same XCD so the A tile is fetched once into that XCD's L2.
__global__ __launch_bounds__(512, 4)
void kan_gemm(const uint8_t* __restrict__ wsA, const uint8_t* __restrict__ wsB,
              float* __restrict__ outg, int row0, int mtPerX)
{
  __shared__ _Float16 As[2][8192];
  __shared__ _Float16 Bs[2][8192];

  const int tid = threadIdx.x, lane = tid & 63, wv = tid >> 6;
  const int wm = wv >> 2, wn = wv & 3;

  const int bid = blockIdx.x;
  const int x = bid & 7;            // XCD (dispatch round-robin)
  const int j = bid >> 3;           // local index on this XCD
  const int kz  = j & 1;            // K-split half
  const int ntI = (j >> 1) & 3;     // n-tile 0..3
  const int mt  = x * mtPerX + (j >> 3);
  const int bm0 = row0 + mt * 128;
  const int bn0 = ntI * 128;
  const int kt0 = kz * 36, kt1 = kt0 + 36;

  char* AsB = (char*)As;
  char* BsB = (char*)Bs;

  uint32_t rdA[4], rdB[2];
  {
    const int rr = lane & 15;
    const uint32_t cc = (uint32_t)(lane >> 4) * 16u;
#pragma unroll
    for (int mi = 0; mi < 4; ++mi)
      rdA[mi] = swz((uint32_t)(wm * 64 + mi * 16 + rr) * 128u + cc);
#pragma unroll
    for (int ni = 0; ni < 2; ++ni)
      rdB[ni] = swz((uint32_t)(wn * 32 + ni * 16 + rr) * 128u + cc);
  }

  floatx4 acc[4][2];
#pragma unroll
  for (int mi = 0; mi < 4; ++mi)
#pragma unroll
    for (int ni = 0; ni < 2; ++ni)
      acc[mi][ni] = (floatx4){0.f, 0.f, 0.f, 0.f};

  auto STAGE = [&](int kt, int nb) {
    const uint8_t* sa = wsA + (size_t)(mt * KT_TOTAL + kt) * TILE_B + (size_t)tid * 16;
    const uint8_t* sb = wsB + (size_t)(kt * 4 + ntI) * TILE_B + (size_t)tid * 16;
    char* da = AsB + nb * TILE_B + tid * 16;
    char* db = BsB + nb * TILE_B + tid * 16;
    __builtin_amdgcn_global_load_lds((const __attribute__((address_space(1))) uint32_t*)sa,
                                     (__attribute__((address_space(3))) uint32_t*)da, 16, 0, 0);
    __builtin_amdgcn_global_load_lds((const __attribute__((address_space(1))) uint32_t*)(sa + 8192),
                                     (__attribute__((address_space(3))) uint32_t*)(da + 8192), 16, 0, 0);
    __builtin_amdgcn_global_load_lds((const __attribute__((address_space(1))) uint32_t*)sb,
                                     (__attribute__((address_space(3))) uint32_t*)db, 16, 0, 0);
    __builtin_amdgcn_global_load_lds((const __attribute__((address_space(1))) uint32_t*)(sb + 8192),
                                     (__attribute__((address_space(3))) uint32_t*)(db + 8192), 16, 0, 0);
  };

  auto COMPUTE = [&](int cb) {
    const char* ab = AsB + cb * TILE_B;
    const char* bb = BsB + cb * TILE_B;
#pragma unroll
    for (int kk = 0; kk < 2; ++kk) {
      const uint32_t ko = (uint32_t)(kk * 64);
      half8 a[4], b[2];
#pragma unroll
      for (int mi = 0; mi < 4; ++mi)
        a[mi] = *(const half8*)(ab + (rdA[mi] ^ ko));   // XOR: swizzle-safe
#pragma unroll
      for (int ni = 0; ni < 2; ++ni)
        b[ni] = *(const half8*)(bb + (rdB[ni] ^ ko));
#pragma unroll
      for (int mi = 0; mi < 4; ++mi)
#pragma unroll
        for (int ni = 0; ni < 2; ++ni)
          acc[mi][ni] = __builtin_amdgcn_mfma_f32_16x16x32_f16(a[mi], b[ni], acc[mi][ni], 0, 0, 0);
    }
  };

  STAGE(kt0, 0);
  __syncthreads();
#pragma unroll 1
  for (int kt = kt0; kt < kt1; ++kt) {
    const int cur = (kt - kt0) & 1;
    if (kt + 1 < kt1) STAGE(kt + 1, cur ^ 1);   // async DMA overlaps COMPUTE
    COMPUTE(cur);
    __syncthreads();                            // one barrier per K-step
  }

  // epilogue: C/D col=lane&15, row=(lane>>4)*4+e ; split-K atomic accumulate
  const int er = (lane >> 4) * 4;
  const int ec = lane & 15;
#pragma unroll
  for (int mi = 0; mi < 4; ++mi) {
#pragma unroll
    for (int ni = 0; ni < 2; ++ni) {
      const size_t base = (size_t)(bm0 + wm * 64 + mi * 16 + er) * NF
                        + (size_t)(bn0 + wn * 32 + ni * 16 + ec);
#pragma unroll
      for (int e = 0; e < 4; ++e)
        unsafeAtomicAdd(outg + base + (size_t)e * NF, acc[mi][ni][e]);
    }
  }
}

extern "C" void kernel_launch(void* const* d_in, const int* in_sizes, int n_in,
                              void* d_out, int out_size, void* d_ws, size_t ws_size,
                              hipStream_t stream) {
  const float* x  = (const float*)d_in[0];
  const float* bw = (const float*)d_in[1];
  const float* sw = (const float*)d_in[2];
  float* out = (float*)d_out;
  uint8_t* wsB = (uint8_t*)d_ws;
  uint8_t* wsA = wsB + B_WS_BYTES;

  // adaptive M-chunking: A images need R*4608*2 bytes; R>=1024 keeps 8|mt-count
  int R = 8192;
  while (R > 1024 && B_WS_BYTES + (size_t)R * 4608 * 2 > ws_size) R >>= 1;
  const int mtPerX = (R / 128) / 8;

  hipLaunchKernelGGL(kan_zero,  dim3(2048), dim3(256), 0, stream, (float4*)out, out_size / 4);
  hipLaunchKernelGGL(kan_prepB, dim3(1152), dim3(256), 0, stream, bw, sw, wsB);
  for (int r0 = 0; r0 < 8192; r0 += R) {
    hipLaunchKernelGGL(kan_prepA, dim3(R * 576 / 256), dim3(256), 0, stream, x, wsA, r0);
    hipLaunchKernelGGL(kan_gemm,  dim3(R / 16), dim3(512), 0, stream, wsA, wsB, out, r0, mtPerX);
  }
}